// Round 7
// baseline (844.090 us; speedup 1.0000x reference)
//
#include <hip/hip_runtime.h>

#define NN 100000
#define NE 1600000
#define NG 512
#define FIN 64
#define HD 128
#define NSTEP 6

// ---- bucketed CSR build geometry ----
#define BROWS 128               // dst nodes per bucket
#define NBUCK 782               // ceil(NN/BROWS)
#define BCAP 3072               // fixed pairs-capacity per bucket (mean 2048, sigma~45 -> 22-sigma headroom)
#define EPER 16                 // edges per thread in k_bin
#define BINBLK 391              // ceil(NE / (256*EPER))

typedef _Float16 f16x8 __attribute__((ext_vector_type(8)));
typedef _Float16 f16x4 __attribute__((ext_vector_type(4)));
typedef float    f32x4 __attribute__((ext_vector_type(4)));

__device__ __forceinline__ float sigm(float x) { return 1.f / (1.f + __expf(-x)); }
__device__ __forceinline__ float tanhfast(float x) { return 2.f / (1.f + __expf(-2.f * x)) - 1.f; }

// LDS tile index with XOR swizzle (128-col tiles, 16B chunks)
__device__ __forceinline__ int lidx(int r, int col) {
    return r * 128 + ((((col >> 3) ^ (r & 15)) << 3) | (col & 7));
}

// async global->LDS 16B DMA: linear LDS dest (wave-uniform base + lane*16),
// per-lane (pre-swizzled) global source. [rule #21: swizzle on SOURCE, not dest]
__device__ __forceinline__ void glds16(const _Float16* g, _Float16* l) {
    __builtin_amdgcn_global_load_lds(
        (const __attribute__((address_space(1))) void*)g,
        (__attribute__((address_space(3))) void*)l, 16, 0, 0);
}

// ---------------- CSR build ----------------
// [R0: direct-scatter fill = 105MB write-amp, 126us. R1: bucketed 2-phase = ~25us.
//  R5: k_count + 3-kernel scan ELIMINATED via fixed-BCAP bucket windows (saved 70us). KEEP.]

// phase 1: bin (src,dst) pairs into fixed-capacity per-bucket windows
__global__ void __launch_bounds__(256) k_bin(const int* __restrict__ src, const int* __restrict__ dst,
                                             int* __restrict__ bcur, int2* __restrict__ pairs) {
    __shared__ int hist[NBUCK];
    __shared__ int base[NBUCK];
    int tid = threadIdx.x;
    for (int i = tid; i < NBUCK; i += 256) hist[i] = 0;
    __syncthreads();
    int e0 = blockIdx.x * (256 * EPER) + tid;
    int s[EPER], d[EPER], rk[EPER];
#pragma unroll
    for (int k = 0; k < EPER; ++k) {
        int e = e0 + k * 256;
        if (e < NE) {
            s[k] = src[e];
            d[k] = dst[e];
            rk[k] = atomicAdd(&hist[d[k] >> 7], 1);   // LDS atomic: local rank within (block,bucket)
        }
    }
    __syncthreads();
    for (int i = tid; i < NBUCK; i += 256) {
        int c = hist[i];
        base[i] = c ? atomicAdd(&bcur[i], c) : 0;     // one global atomic per (block,bucket); bcur starts at 0
    }
    __syncthreads();
#pragma unroll
    for (int k = 0; k < EPER; ++k) {
        int e = e0 + k * 256;
        if (e < NE) {
            int b = d[k] >> 7;
            pairs[(size_t)b * BCAP + base[b] + rk[k]] = make_int2(s[k], d[k]);
        }
    }
}

// scan 782 bucket counts -> bucket bases (1 block, 1024 threads)
__global__ void k_bscan(const int* __restrict__ bcnt, int* __restrict__ bbase) {
    __shared__ int sh[1024];
    int tid = threadIdx.x;
    int v = (tid < NBUCK) ? bcnt[tid] : 0;
    sh[tid] = v;
    __syncthreads();
    for (int off = 1; off < 1024; off <<= 1) {
        int t = (tid >= off) ? sh[tid - off] : 0;
        __syncthreads();
        sh[tid] += t;
        __syncthreads();
    }
    if (tid < NBUCK) bbase[tid] = sh[tid] - v;
    if (tid == NBUCK - 1) bbase[NBUCK] = sh[tid];    // = NE
}

// phase 2: one block per bucket; rebuild per-node indptr + dense csr window
__global__ void __launch_bounds__(256) k_fill2(const int2* __restrict__ pairs,
                                               const int* __restrict__ bcnt,
                                               const int* __restrict__ bbase,
                                               int* __restrict__ indptr,
                                               int* __restrict__ csr) {
    __shared__ int cnt[BROWS];
    __shared__ int ip[BROWS];
    __shared__ int sc[BROWS];
    int b = blockIdx.x, tid = threadIdx.x;
    int n0 = b * BROWS;
    if (tid < BROWS) cnt[tid] = 0;
    __syncthreads();
    int ec = bcnt[b];
    const int2* pw = pairs + (size_t)b * BCAP;
    // pass A: per-node counts within bucket
    for (int i = tid; i < ec; i += 256)
        atomicAdd(&cnt[pw[i].y & (BROWS - 1)], 1);
    __syncthreads();
    // exclusive scan of 128 counts
    if (tid < BROWS) sc[tid] = cnt[tid];
    __syncthreads();
    for (int off = 1; off < BROWS; off <<= 1) {
        int t = (tid < BROWS && tid >= off) ? sc[tid - off] : 0;
        __syncthreads();
        if (tid < BROWS) sc[tid] += t;
        __syncthreads();
    }
    int base = bbase[b];
    if (tid < BROWS) {
        int v = base + sc[tid] - cnt[tid];
        ip[tid] = v;
        int n = n0 + tid;
        if (n < NN) indptr[n] = v;
        cnt[tid] = 0;
    }
    if (b == NBUCK - 1 && tid == 0) indptr[NN] = NE;
    __syncthreads();
    // pass B: place edges (bucket window is L2-hot from pass A)
    for (int i = tid; i < ec; i += 256) {
        int2 p = pw[i];
        int li = p.y & (BROWS - 1);
        int r = atomicAdd(&cnt[li], 1);
        csr[ip[li] + r] = p.x;
    }
}

// ---------------- B prep (GRU weights), swizzled to MFMA fragment order ----------------
// Logical Bcat[c][k]: c=0..511 (g=c>>7: 0=r,1=z,2=i_n,3=h_n; j=c&127), k=0..255.
//   k<128:  g!=3 ? Weff[s][k][jj] : 0    (Weff = Wmp[s] @ Wih^T)
//   k>=128: g!=2 ? Whh[jj][k-128] : 0
__global__ void k_prepB(const float* __restrict__ Wmp, const float* __restrict__ Wih,
                        const float* __restrict__ Whh, _Float16* __restrict__ Bsw) {
    __shared__ float wih[HD];
    int b = blockIdx.x;          // s*512 + c
    int s = b >> 9;
    int c = b & 511;
    int g = c >> 7;
    int j = c & 127;
    int jj = (g < 2) ? c : (j + 256);
    int k = threadIdx.x;         // 0..255
    if (k < HD) wih[k] = Wih[(size_t)jj * HD + k];
    __syncthreads();
    float val = 0.f;
    if (k < 128) {
        if (g != 3) {
            const float* wm = Wmp + ((size_t)s * HD + k) * HD;
            float acc = 0.f;
#pragma unroll 8
            for (int t = 0; t < HD; ++t) acc += wm[t] * wih[t];
            val = acc;
        }
    } else {
        if (g != 2) val = Whh[(size_t)jj * HD + (k - 128)];
    }
    int l16 = c & 15, sub = (c >> 4) & 1, w = (c >> 5) & 3;
    int t = g * 2 + sub;
    int p = k >> 5, quad = (k >> 3) & 3, je = k & 7;
    size_t idx = (size_t)s * 131072 + ((size_t)((w * 8 + t) * 8 + p) * 64 + quad * 16 + l16) * 8 + je;
    Bsw[idx] = (_Float16)val;
}

// ---------------- W_in prep: fragment-order hi/lo fp16 ----------------
__global__ void k_prepWin(const float* __restrict__ Win,
                          _Float16* __restrict__ BihW, _Float16* __restrict__ BilW) {
    int gid = blockIdx.x * 256 + threadIdx.x;   // 0..8191
    int jj = gid & 7;
    int lane = (gid >> 3) & 63;
    int p = (gid >> 9) & 1;
    int t = (gid >> 10) & 7;
    int k = p * 32 + (lane >> 4) * 8 + jj;
    int col = t * 16 + (lane & 15);
    float val = Win[(size_t)k * HD + col];
    _Float16 hi = (_Float16)val;
    BihW[gid] = hi;
    BilW[gid] = (_Float16)(val - (float)hi);
}

// ---------------- input layer (MFMA): h = tanh(x @ W_in), fp16 out ----------------
__global__ void __launch_bounds__(256) k_input(const float* __restrict__ x,
                                               const _Float16* __restrict__ BihW,
                                               const _Float16* __restrict__ BilW,
                                               _Float16* __restrict__ H) {
    __shared__ _Float16 Xh[64 * 64];
    __shared__ _Float16 Xl[64 * 64];
    __shared__ _Float16 Oh[64 * 128];
    int tid = threadIdx.x;
    int w = tid >> 6, lane = tid & 63;
    int quad = lane >> 4, l16 = lane & 15;
    int m0 = blockIdx.x * 64;

#pragma unroll
    for (int it = 0; it < 4; ++it) {
        int c = it * 256 + tid;          // 1024 chunks of 4 floats
        int row = c >> 4, cc = c & 15;
        int grow = m0 + row; if (grow >= NN) grow = NN - 1;
        float4 v = ((const float4*)(x + (size_t)grow * FIN))[cc];
        f16x4 vh, vl;
        vh[0] = (_Float16)v.x; vl[0] = (_Float16)(v.x - (float)vh[0]);
        vh[1] = (_Float16)v.y; vl[1] = (_Float16)(v.y - (float)vh[1]);
        vh[2] = (_Float16)v.z; vl[2] = (_Float16)(v.z - (float)vh[2]);
        vh[3] = (_Float16)v.w; vl[3] = (_Float16)(v.w - (float)vh[3]);
        int ld = row * 64 + ((((cc >> 1) ^ (row & 7)) << 3)) + (cc & 1) * 4;
        *(f16x4*)(&Xh[ld]) = vh;
        *(f16x4*)(&Xl[ld]) = vl;
    }
    __syncthreads();

    f32x4 acc[4][2];
#pragma unroll
    for (int mi = 0; mi < 4; ++mi) { acc[mi][0] = (f32x4){0,0,0,0}; acc[mi][1] = (f32x4){0,0,0,0}; }

#pragma unroll
    for (int p = 0; p < 2; ++p) {
        int ch = p * 4 + quad;
        f16x8 ah[4], al[4];
#pragma unroll
        for (int mi = 0; mi < 4; ++mi) {
            int r = mi * 16 + l16;
            int li = r * 64 + ((ch ^ (r & 7)) << 3);
            ah[mi] = *(const f16x8*)(&Xh[li]);
            al[mi] = *(const f16x8*)(&Xl[li]);
        }
#pragma unroll
        for (int t2 = 0; t2 < 2; ++t2) {
            int t = w * 2 + t2;
            f16x8 bh = *(const f16x8*)(BihW + ((size_t)(t * 2 + p) * 64 + lane) * 8);
            f16x8 blv = *(const f16x8*)(BilW + ((size_t)(t * 2 + p) * 64 + lane) * 8);
#pragma unroll
            for (int mi = 0; mi < 4; ++mi) {
                acc[mi][t2] = __builtin_amdgcn_mfma_f32_16x16x32_f16(ah[mi], bh, acc[mi][t2], 0, 0, 0);
                acc[mi][t2] = __builtin_amdgcn_mfma_f32_16x16x32_f16(ah[mi], blv, acc[mi][t2], 0, 0, 0);
                acc[mi][t2] = __builtin_amdgcn_mfma_f32_16x16x32_f16(al[mi], bh, acc[mi][t2], 0, 0, 0);
            }
        }
    }

#pragma unroll
    for (int t2 = 0; t2 < 2; ++t2) {
        int j = (w * 2 + t2) * 16 + l16;
#pragma unroll
        for (int mi = 0; mi < 4; ++mi) {
#pragma unroll
            for (int reg = 0; reg < 4; ++reg) {
                int row = mi * 16 + quad * 4 + reg;
                Oh[lidx(row, j)] = (_Float16)tanhfast(acc[mi][t2][reg]);
            }
        }
    }
    __syncthreads();
#pragma unroll
    for (int it = 0; it < 4; ++it) {
        int c = it * 256 + tid;
        int row = c >> 4, kc = c & 15;
        int grow = m0 + row;
        if (grow < NN) {
            int ld = row * 128 + ((kc ^ (row & 15)) << 3);
            *(f16x8*)(H + (size_t)grow * HD + kc * 8) = *(const f16x8*)(&Oh[ld]);
        }
    }
}

// ---------------- aggregation: S[v] = sum_{in-edges} H[src], fp16 out ----------------
// [R2: fusing into GEMM regressed (needs max TLP) -- KEEP SPLIT.
//  R6 post-mortem: doubling per-lane loads-in-flight + pk_add pre-reduce cut VALUBusy
//  38->29% but dur FLAT (58.5->59.5) -> not MLP/VALU-bound. FETCH 177MB == the
//  cross-XCD distinct-row floor (86.5K rows x 8 XCDs) exactly; L2-miss-path BW
//  ceiling. STRUCTURAL ROOFLINE at ~58us -- reverted to R5 form, do not touch.]
__global__ void k_agg(const _Float16* __restrict__ H, const int* __restrict__ indptr,
                      const int* __restrict__ csr, _Float16* __restrict__ Shi) {
    int v = blockIdx.x * 4 + (threadIdx.x >> 6);
    int lane = threadIdx.x & 63;
    int slot = lane >> 4;
    int cg = lane & 15;
    const _Float16* hp = H + cg * 8;
    int s = indptr[v], e = indptr[v + 1];
    float a0 = 0.f, a1 = 0.f, a2 = 0.f, a3 = 0.f, a4 = 0.f, a5 = 0.f, a6 = 0.f, a7 = 0.f;
    int i = s + slot;
    for (; i + 12 < e; i += 16) {
        int u0 = csr[i], u1 = csr[i + 4], u2 = csr[i + 8], u3 = csr[i + 12];
        f16x8 t0 = *(const f16x8*)(hp + (size_t)u0 * HD);
        f16x8 t1 = *(const f16x8*)(hp + (size_t)u1 * HD);
        f16x8 t2 = *(const f16x8*)(hp + (size_t)u2 * HD);
        f16x8 t3 = *(const f16x8*)(hp + (size_t)u3 * HD);
        a0 += (float)t0[0] + (float)t1[0] + (float)t2[0] + (float)t3[0];
        a1 += (float)t0[1] + (float)t1[1] + (float)t2[1] + (float)t3[1];
        a2 += (float)t0[2] + (float)t1[2] + (float)t2[2] + (float)t3[2];
        a3 += (float)t0[3] + (float)t1[3] + (float)t2[3] + (float)t3[3];
        a4 += (float)t0[4] + (float)t1[4] + (float)t2[4] + (float)t3[4];
        a5 += (float)t0[5] + (float)t1[5] + (float)t2[5] + (float)t3[5];
        a6 += (float)t0[6] + (float)t1[6] + (float)t2[6] + (float)t3[6];
        a7 += (float)t0[7] + (float)t1[7] + (float)t2[7] + (float)t3[7];
    }
    for (; i < e; i += 4) {
        int u0 = csr[i];
        f16x8 t0 = *(const f16x8*)(hp + (size_t)u0 * HD);
        a0 += (float)t0[0]; a1 += (float)t0[1]; a2 += (float)t0[2]; a3 += (float)t0[3];
        a4 += (float)t0[4]; a5 += (float)t0[5]; a6 += (float)t0[6]; a7 += (float)t0[7];
    }
    a0 += __shfl_down(a0, 32); a1 += __shfl_down(a1, 32);
    a2 += __shfl_down(a2, 32); a3 += __shfl_down(a3, 32);
    a4 += __shfl_down(a4, 32); a5 += __shfl_down(a5, 32);
    a6 += __shfl_down(a6, 32); a7 += __shfl_down(a7, 32);
    a0 += __shfl_down(a0, 16); a1 += __shfl_down(a1, 16);
    a2 += __shfl_down(a2, 16); a3 += __shfl_down(a3, 16);
    a4 += __shfl_down(a4, 16); a5 += __shfl_down(a5, 16);
    a6 += __shfl_down(a6, 16); a7 += __shfl_down(a7, 16);
    if (lane < 16) {
        f16x8 o;
        o[0] = (_Float16)a0; o[1] = (_Float16)a1; o[2] = (_Float16)a2; o[3] = (_Float16)a3;
        o[4] = (_Float16)a4; o[5] = (_Float16)a5; o[6] = (_Float16)a6; o[7] = (_Float16)a7;
        *(f16x8*)(Shi + (size_t)v * HD + cg * 8) = o;
    }
}

// ---------------- fused MFMA GEMM + GRU gates (H fp16, in place) ----------------
// [R2: 64-row tile = 212 regs -> 2 blk/CU, 81us. R3: 32-row, acc[2][8], reg-staged H
//  -> ~53us at 3 waves/SIMD (~148 regs). R7: global_load_lds staging for Sl AND Hh
//  (linear LDS dest + inverse-swizzled per-lane global src, rule #21) deletes the
//  staging VGPRs + hreg + mid-barrier -> target <=128 regs, launch_bounds(256,4)
//  = 4 waves/SIMD. Async DMA + higher occupancy replace the hreg-defer trick.]
__global__ void __launch_bounds__(256, 4) k_ggemm(
        const _Float16* __restrict__ Shi, _Float16* __restrict__ H,
        const _Float16* __restrict__ Bsw,
        const float* __restrict__ bih, const float* __restrict__ bhh) {
    __shared__ _Float16 Sl[32 * 128];
    __shared__ _Float16 Hh[32 * 128];
    int tid = threadIdx.x;
    int w = tid >> 6, lane = tid & 63;
    int quad = lane >> 4, l16 = lane & 15;
    int m0 = blockIdx.x * 32;

    // async stage: LDS linear, global source inverse-swizzled so LDS chunk (row,kcs)
    // holds H[row, (kcs^(row&15))*8 ..] -- matches lidx() on the read side.
#pragma unroll
    for (int it = 0; it < 2; ++it) {
        int c = it * 256 + tid;
        int row = c >> 4, kcs = c & 15;
        int kc = kcs ^ (row & 15);
        size_t gsrc = (size_t)(m0 + row) * HD + kc * 8;
        int lbase = (it * 256 + (tid & 192)) * 8;     // wave-uniform; HW adds lane*16B
        glds16(Shi + gsrc, &Sl[lbase]);
        glds16(H + gsrc, &Hh[lbase]);
    }
    __syncthreads();

    f32x4 acc[2][8];
#pragma unroll
    for (int mi = 0; mi < 2; ++mi)
#pragma unroll
        for (int t = 0; t < 8; ++t) acc[mi][t] = (f32x4){0.f, 0.f, 0.f, 0.f};

    const _Float16* bw = Bsw + (size_t)(w * 8) * 8 * 512 + lane * 8;

    // S phases (gates r,z,i_n -> t=0..5)
#pragma unroll
    for (int p = 0; p < 4; ++p) {
        f16x8 a[2];
#pragma unroll
        for (int mi = 0; mi < 2; ++mi)
            a[mi] = *(const f16x8*)(&Sl[lidx(mi * 16 + l16, p * 32 + quad * 8)]);
#pragma unroll
        for (int t = 0; t < 6; ++t) {
            f16x8 b = *(const f16x8*)(bw + (size_t)(t * 8 + p) * 512);
#pragma unroll
            for (int mi = 0; mi < 2; ++mi)
                acc[mi][t] = __builtin_amdgcn_mfma_f32_16x16x32_f16(a[mi], b, acc[mi][t], 0, 0, 0);
        }
    }

    // H phases (gates r,z,h_n -> t={0,1,2,3,6,7})
#pragma unroll
    for (int p = 0; p < 4; ++p) {
        f16x8 a[2];
#pragma unroll
        for (int mi = 0; mi < 2; ++mi)
            a[mi] = *(const f16x8*)(&Hh[lidx(mi * 16 + l16, p * 32 + quad * 8)]);
#pragma unroll
        for (int tt = 0; tt < 6; ++tt) {
            int t = (tt < 4) ? tt : (tt + 2);
            f16x8 b = *(const f16x8*)(bw + (size_t)(t * 8 + p + 4) * 512);
#pragma unroll
            for (int mi = 0; mi < 2; ++mi)
                acc[mi][t] = __builtin_amdgcn_mfma_f32_16x16x32_f16(a[mi], b, acc[mi][t], 0, 0, 0);
        }
    }

    __syncthreads();   // all H-LDS A-reads done before epilogue overwrites Hh

    // epilogue: gates; in-place RMW on Hh (each li touched by exactly one thread)
#pragma unroll
    for (int ns = 0; ns < 2; ++ns) {
        int j = w * 32 + ns * 16 + l16;
        float br  = bih[j]       + bhh[j];
        float bz  = bih[j + 128] + bhh[j + 128];
        float bin = bih[j + 256];
        float bhn = bhh[j + 256];
#pragma unroll
        for (int mi = 0; mi < 2; ++mi) {
#pragma unroll
            for (int reg = 0; reg < 4; ++reg) {
                int row = mi * 16 + quad * 4 + reg;
                int li = lidx(row, j);
                float hold = (float)Hh[li];
                float r = sigm(acc[mi][0 + ns][reg] + br);
                float z = sigm(acc[mi][2 + ns][reg] + bz);
                float n = tanhfast(acc[mi][4 + ns][reg] + bin + r * (acc[mi][6 + ns][reg] + bhn));
                Hh[li] = (_Float16)((1.f - z) * n + z * hold);
            }
        }
    }
    __syncthreads();

#pragma unroll
    for (int it = 0; it < 2; ++it) {
        int c = it * 256 + tid;
        int row = c >> 4, kc = c & 15;
        int grow = m0 + row;
        int ld = row * 128 + ((kc ^ (row & 15)) << 3);
        *(f16x8*)(H + (size_t)grow * HD + kc * 8) = *(const f16x8*)(&Hh[ld]);
    }
}

// ---------------- pooling + head ----------------
__global__ void k_ginit(int* __restrict__ gs, int* __restrict__ ge) {
    int g = threadIdx.x;
    if (g < NG) { gs[g] = 0; ge[g] = 0; }
}

__global__ void k_bounds(const int* __restrict__ batch, int* __restrict__ gs, int* __restrict__ ge) {
    int i = blockIdx.x * 256 + threadIdx.x;
    if (i >= NN) return;
    int b = batch[i];
    if (i == 0 || batch[i - 1] != b) gs[b] = i;
    if (i == NN - 1 || batch[i + 1] != b) ge[b] = i + 1;
}

// [R3: old k_pool (scalar 2B loads, serial loop) was 68us, Occ 8%. R4: slot x colgroup
//  f16x8 restructure -> out of top-5. KEEP.]
__global__ void __launch_bounds__(256) k_pool(const _Float16* __restrict__ H,
                       const int* __restrict__ gs, const int* __restrict__ ge,
                       const float* __restrict__ Wp, const float* __restrict__ bp,
                       float* __restrict__ out) {
    __shared__ float red[4][HD];
    __shared__ float red2[HD];
    int g = blockIdx.x, tid = threadIdx.x;
    int w = tid >> 6, lane = tid & 63;
    int slot = tid >> 4;        // 0..15 (global node-slot)
    int cg = tid & 15;          // col-group of 8
    int s = gs[g], e = ge[g];
    float a0 = 0.f, a1 = 0.f, a2 = 0.f, a3 = 0.f, a4 = 0.f, a5 = 0.f, a6 = 0.f, a7 = 0.f;
    for (int n = s + slot; n < e; n += 16) {
        f16x8 v = *(const f16x8*)(H + (size_t)n * HD + cg * 8);
        a0 += (float)v[0]; a1 += (float)v[1]; a2 += (float)v[2]; a3 += (float)v[3];
        a4 += (float)v[4]; a5 += (float)v[5]; a6 += (float)v[6]; a7 += (float)v[7];
    }
    // reduce the 4 slot-locals within each wave
    a0 += __shfl_down(a0, 32); a1 += __shfl_down(a1, 32);
    a2 += __shfl_down(a2, 32); a3 += __shfl_down(a3, 32);
    a4 += __shfl_down(a4, 32); a5 += __shfl_down(a5, 32);
    a6 += __shfl_down(a6, 32); a7 += __shfl_down(a7, 32);
    a0 += __shfl_down(a0, 16); a1 += __shfl_down(a1, 16);
    a2 += __shfl_down(a2, 16); a3 += __shfl_down(a3, 16);
    a4 += __shfl_down(a4, 16); a5 += __shfl_down(a5, 16);
    a6 += __shfl_down(a6, 16); a7 += __shfl_down(a7, 16);
    if (lane < 16) {
        red[w][cg * 8 + 0] = a0; red[w][cg * 8 + 1] = a1;
        red[w][cg * 8 + 2] = a2; red[w][cg * 8 + 3] = a3;
        red[w][cg * 8 + 4] = a4; red[w][cg * 8 + 5] = a5;
        red[w][cg * 8 + 6] = a6; red[w][cg * 8 + 7] = a7;
    }
    __syncthreads();
    if (tid < HD) {
        int cnt = e - s;
        float pooled = (red[0][tid] + red[1][tid] + red[2][tid] + red[3][tid])
                       / (float)(cnt > 0 ? cnt : 1);
        red2[tid] = fmaxf(pooled, 0.f) * Wp[tid];
    }
    __syncthreads();
    for (int off = 64; off > 0; off >>= 1) {
        if (tid < off) red2[tid] += red2[tid + off];
        __syncthreads();
    }
    if (tid == 0) out[g] = red2[0] + bp[0];
}

extern "C" void kernel_launch(void* const* d_in, const int* in_sizes, int n_in,
                              void* d_out, int out_size, void* d_ws, size_t ws_size,
                              hipStream_t stream) {
    const float* x   = (const float*)d_in[0];
    const int*   ei  = (const int*)d_in[1];
    const int*   bat = (const int*)d_in[2];
    const float* Win = (const float*)d_in[3];
    const float* Wmp = (const float*)d_in[4];
    const float* Wih = (const float*)d_in[5];
    const float* Whh = (const float*)d_in[6];
    const float* bih = (const float*)d_in[7];
    const float* bhh = (const float*)d_in[8];
    const float* Wp  = (const float*)d_in[9];
    const float* bp  = (const float*)d_in[10];
    float* out = (float*)d_out;

    const int* esrc = ei;
    const int* edst = ei + NE;

    char* w = (char*)d_ws;
    _Float16* H   = (_Float16*)w; w += (size_t)NN * HD * 2;
    _Float16* Shi = (_Float16*)w; w += (size_t)NN * HD * 2;
    _Float16* Bsw = (_Float16*)w; w += (size_t)NSTEP * 131072 * 2;
    _Float16* BihW = (_Float16*)w; w += 8192 * 2;
    _Float16* BilW = (_Float16*)w; w += 8192 * 2;
    int* indptr  = (int*)w;   w += 400128;
    int* scratch = (int*)w;   w += 400128;   // bcur (782) @ +0; bbase (783) @ +1024
    int* csr     = (int*)w;   w += (size_t)NE * 4;
    int* gs      = (int*)w;   w += NG * 4;
    int* ge      = (int*)w;   w += NG * 4;

    int*  bcur  = scratch;
    int*  bbase = scratch + 1024;
    // pairs buffer aliases Shi (19.2MB < 25.6MB; consumed by k_fill2 before first k_agg)
    int2* pairs = (int2*)Shi;

    // CSR build: bin into fixed-cap bucket windows -> 782-scan -> per-bucket indptr+fill
    hipMemsetAsync(bcur, 0, NBUCK * 4, stream);
    k_bin<<<BINBLK, 256, 0, stream>>>(esrc, edst, bcur, pairs);
    k_bscan<<<1, 1024, 0, stream>>>(bcur, bbase);
    k_fill2<<<NBUCK, 256, 0, stream>>>(pairs, bcur, bbase, indptr, csr);

    // weight prep + input layer
    k_prepB<<<NSTEP * 512, 256, 0, stream>>>(Wmp, Wih, Whh, Bsw);
    k_prepWin<<<32, 256, 0, stream>>>(Win, BihW, BilW);
    k_input<<<(NN + 63) / 64, 256, 0, stream>>>(x, BihW, BilW, H);

    // 6 message-passing + fused GEMM/GRU steps (H updated in place)
    for (int st = 0; st < NSTEP; ++st) {
        k_agg<<<NN / 4, 256, 0, stream>>>(H, indptr, csr, Shi);
        k_ggemm<<<NN / 32, 256, 0, stream>>>(Shi, H,
                                             Bsw + (size_t)st * 131072,
                                             bih, bhh);
    }

    // pooling + head
    k_ginit<<<1, NG, 0, stream>>>(gs, ge);
    k_bounds<<<(NN + 255) / 256, 256, 0, stream>>>(bat, gs, ge);
    k_pool<<<NG, 256, 0, stream>>>(H, gs, ge, Wp, bp, out);
}

// Round 8
// 807.434 us; speedup vs baseline: 1.0454x; 1.0454x over previous
//
#include <hip/hip_runtime.h>

#define NN 100000
#define NE 1600000
#define NG 512
#define FIN 64
#define HD 128
#define NSTEP 6

// ---- bucketed CSR build geometry ----
#define BROWS 128               // dst nodes per bucket
#define NBUCK 782               // ceil(NN/BROWS)
#define BCAP 3072               // fixed pairs-capacity per bucket (mean 2048, sigma~45 -> 22-sigma headroom)
#define EPER 16                 // edges per thread in k_bin
#define BINBLK 391              // ceil(NE / (256*EPER))

typedef _Float16 f16x8 __attribute__((ext_vector_type(8)));
typedef _Float16 f16x4 __attribute__((ext_vector_type(4)));
typedef float    f32x4 __attribute__((ext_vector_type(4)));

__device__ __forceinline__ float sigm(float x) { return 1.f / (1.f + __expf(-x)); }
__device__ __forceinline__ float tanhfast(float x) { return 2.f / (1.f + __expf(-2.f * x)) - 1.f; }

// LDS tile index with XOR swizzle (128-col tiles, 16B chunks)
__device__ __forceinline__ int lidx(int r, int col) {
    return r * 128 + ((((col >> 3) ^ (r & 15)) << 3) | (col & 7));
}

// ---------------- CSR build ----------------
// [R0: direct-scatter fill = 105MB write-amp, 126us. R1: bucketed 2-phase = ~25us.
//  R5: k_count + 3-kernel scan ELIMINATED via fixed-BCAP bucket windows (saved 70us). KEEP.]

// phase 1: bin (src,dst) pairs into fixed-capacity per-bucket windows
__global__ void __launch_bounds__(256) k_bin(const int* __restrict__ src, const int* __restrict__ dst,
                                             int* __restrict__ bcur, int2* __restrict__ pairs) {
    __shared__ int hist[NBUCK];
    __shared__ int base[NBUCK];
    int tid = threadIdx.x;
    for (int i = tid; i < NBUCK; i += 256) hist[i] = 0;
    __syncthreads();
    int e0 = blockIdx.x * (256 * EPER) + tid;
    int s[EPER], d[EPER], rk[EPER];
#pragma unroll
    for (int k = 0; k < EPER; ++k) {
        int e = e0 + k * 256;
        if (e < NE) {
            s[k] = src[e];
            d[k] = dst[e];
            rk[k] = atomicAdd(&hist[d[k] >> 7], 1);   // LDS atomic: local rank within (block,bucket)
        }
    }
    __syncthreads();
    for (int i = tid; i < NBUCK; i += 256) {
        int c = hist[i];
        base[i] = c ? atomicAdd(&bcur[i], c) : 0;     // one global atomic per (block,bucket); bcur starts at 0
    }
    __syncthreads();
#pragma unroll
    for (int k = 0; k < EPER; ++k) {
        int e = e0 + k * 256;
        if (e < NE) {
            int b = d[k] >> 7;
            pairs[(size_t)b * BCAP + base[b] + rk[k]] = make_int2(s[k], d[k]);
        }
    }
}

// scan 782 bucket counts -> bucket bases (1 block, 1024 threads)
__global__ void k_bscan(const int* __restrict__ bcnt, int* __restrict__ bbase) {
    __shared__ int sh[1024];
    int tid = threadIdx.x;
    int v = (tid < NBUCK) ? bcnt[tid] : 0;
    sh[tid] = v;
    __syncthreads();
    for (int off = 1; off < 1024; off <<= 1) {
        int t = (tid >= off) ? sh[tid - off] : 0;
        __syncthreads();
        sh[tid] += t;
        __syncthreads();
    }
    if (tid < NBUCK) bbase[tid] = sh[tid] - v;
    if (tid == NBUCK - 1) bbase[NBUCK] = sh[tid];    // = NE
}

// phase 2: one block per bucket; rebuild per-node indptr + dense csr window
__global__ void __launch_bounds__(256) k_fill2(const int2* __restrict__ pairs,
                                               const int* __restrict__ bcnt,
                                               const int* __restrict__ bbase,
                                               int* __restrict__ indptr,
                                               int* __restrict__ csr) {
    __shared__ int cnt[BROWS];
    __shared__ int ip[BROWS];
    __shared__ int sc[BROWS];
    int b = blockIdx.x, tid = threadIdx.x;
    int n0 = b * BROWS;
    if (tid < BROWS) cnt[tid] = 0;
    __syncthreads();
    int ec = bcnt[b];
    const int2* pw = pairs + (size_t)b * BCAP;
    // pass A: per-node counts within bucket
    for (int i = tid; i < ec; i += 256)
        atomicAdd(&cnt[pw[i].y & (BROWS - 1)], 1);
    __syncthreads();
    // exclusive scan of 128 counts
    if (tid < BROWS) sc[tid] = cnt[tid];
    __syncthreads();
    for (int off = 1; off < BROWS; off <<= 1) {
        int t = (tid < BROWS && tid >= off) ? sc[tid - off] : 0;
        __syncthreads();
        if (tid < BROWS) sc[tid] += t;
        __syncthreads();
    }
    int base = bbase[b];
    if (tid < BROWS) {
        int v = base + sc[tid] - cnt[tid];
        ip[tid] = v;
        int n = n0 + tid;
        if (n < NN) indptr[n] = v;
        cnt[tid] = 0;
    }
    if (b == NBUCK - 1 && tid == 0) indptr[NN] = NE;
    __syncthreads();
    // pass B: place edges (bucket window is L2-hot from pass A)
    for (int i = tid; i < ec; i += 256) {
        int2 p = pw[i];
        int li = p.y & (BROWS - 1);
        int r = atomicAdd(&cnt[li], 1);
        csr[ip[li] + r] = p.x;
    }
}

// ---------------- B prep (GRU weights), swizzled to MFMA fragment order ----------------
// Logical Bcat[c][k]: c=0..511 (g=c>>7: 0=r,1=z,2=i_n,3=h_n; j=c&127), k=0..255.
//   k<128:  g!=3 ? Weff[s][k][jj] : 0    (Weff = Wmp[s] @ Wih^T)
//   k>=128: g!=2 ? Whh[jj][k-128] : 0
__global__ void k_prepB(const float* __restrict__ Wmp, const float* __restrict__ Wih,
                        const float* __restrict__ Whh, _Float16* __restrict__ Bsw) {
    __shared__ float wih[HD];
    int b = blockIdx.x;          // s*512 + c
    int s = b >> 9;
    int c = b & 511;
    int g = c >> 7;
    int j = c & 127;
    int jj = (g < 2) ? c : (j + 256);
    int k = threadIdx.x;         // 0..255
    if (k < HD) wih[k] = Wih[(size_t)jj * HD + k];
    __syncthreads();
    float val = 0.f;
    if (k < 128) {
        if (g != 3) {
            const float* wm = Wmp + ((size_t)s * HD + k) * HD;
            float acc = 0.f;
#pragma unroll 8
            for (int t = 0; t < HD; ++t) acc += wm[t] * wih[t];
            val = acc;
        }
    } else {
        if (g != 2) val = Whh[(size_t)jj * HD + (k - 128)];
    }
    int l16 = c & 15, sub = (c >> 4) & 1, w = (c >> 5) & 3;
    int t = g * 2 + sub;
    int p = k >> 5, quad = (k >> 3) & 3, je = k & 7;
    size_t idx = (size_t)s * 131072 + ((size_t)((w * 8 + t) * 8 + p) * 64 + quad * 16 + l16) * 8 + je;
    Bsw[idx] = (_Float16)val;
}

// ---------------- W_in prep: fragment-order hi/lo fp16 ----------------
__global__ void k_prepWin(const float* __restrict__ Win,
                          _Float16* __restrict__ BihW, _Float16* __restrict__ BilW) {
    int gid = blockIdx.x * 256 + threadIdx.x;   // 0..8191
    int jj = gid & 7;
    int lane = (gid >> 3) & 63;
    int p = (gid >> 9) & 1;
    int t = (gid >> 10) & 7;
    int k = p * 32 + (lane >> 4) * 8 + jj;
    int col = t * 16 + (lane & 15);
    float val = Win[(size_t)k * HD + col];
    _Float16 hi = (_Float16)val;
    BihW[gid] = hi;
    BilW[gid] = (_Float16)(val - (float)hi);
}

// ---------------- input layer (MFMA): h = tanh(x @ W_in), fp16 out ----------------
__global__ void __launch_bounds__(256) k_input(const float* __restrict__ x,
                                               const _Float16* __restrict__ BihW,
                                               const _Float16* __restrict__ BilW,
                                               _Float16* __restrict__ H) {
    __shared__ _Float16 Xh[64 * 64];
    __shared__ _Float16 Xl[64 * 64];
    __shared__ _Float16 Oh[64 * 128];
    int tid = threadIdx.x;
    int w = tid >> 6, lane = tid & 63;
    int quad = lane >> 4, l16 = lane & 15;
    int m0 = blockIdx.x * 64;

#pragma unroll
    for (int it = 0; it < 4; ++it) {
        int c = it * 256 + tid;          // 1024 chunks of 4 floats
        int row = c >> 4, cc = c & 15;
        int grow = m0 + row; if (grow >= NN) grow = NN - 1;
        float4 v = ((const float4*)(x + (size_t)grow * FIN))[cc];
        f16x4 vh, vl;
        vh[0] = (_Float16)v.x; vl[0] = (_Float16)(v.x - (float)vh[0]);
        vh[1] = (_Float16)v.y; vl[1] = (_Float16)(v.y - (float)vh[1]);
        vh[2] = (_Float16)v.z; vl[2] = (_Float16)(v.z - (float)vh[2]);
        vh[3] = (_Float16)v.w; vl[3] = (_Float16)(v.w - (float)vh[3]);
        int ld = row * 64 + ((((cc >> 1) ^ (row & 7)) << 3)) + (cc & 1) * 4;
        *(f16x4*)(&Xh[ld]) = vh;
        *(f16x4*)(&Xl[ld]) = vl;
    }
    __syncthreads();

    f32x4 acc[4][2];
#pragma unroll
    for (int mi = 0; mi < 4; ++mi) { acc[mi][0] = (f32x4){0,0,0,0}; acc[mi][1] = (f32x4){0,0,0,0}; }

#pragma unroll
    for (int p = 0; p < 2; ++p) {
        int ch = p * 4 + quad;
        f16x8 ah[4], al[4];
#pragma unroll
        for (int mi = 0; mi < 4; ++mi) {
            int r = mi * 16 + l16;
            int li = r * 64 + ((ch ^ (r & 7)) << 3);
            ah[mi] = *(const f16x8*)(&Xh[li]);
            al[mi] = *(const f16x8*)(&Xl[li]);
        }
#pragma unroll
        for (int t2 = 0; t2 < 2; ++t2) {
            int t = w * 2 + t2;
            f16x8 bh = *(const f16x8*)(BihW + ((size_t)(t * 2 + p) * 64 + lane) * 8);
            f16x8 blv = *(const f16x8*)(BilW + ((size_t)(t * 2 + p) * 64 + lane) * 8);
#pragma unroll
            for (int mi = 0; mi < 4; ++mi) {
                acc[mi][t2] = __builtin_amdgcn_mfma_f32_16x16x32_f16(ah[mi], bh, acc[mi][t2], 0, 0, 0);
                acc[mi][t2] = __builtin_amdgcn_mfma_f32_16x16x32_f16(ah[mi], blv, acc[mi][t2], 0, 0, 0);
                acc[mi][t2] = __builtin_amdgcn_mfma_f32_16x16x32_f16(al[mi], bh, acc[mi][t2], 0, 0, 0);
            }
        }
    }

#pragma unroll
    for (int t2 = 0; t2 < 2; ++t2) {
        int j = (w * 2 + t2) * 16 + l16;
#pragma unroll
        for (int mi = 0; mi < 4; ++mi) {
#pragma unroll
            for (int reg = 0; reg < 4; ++reg) {
                int row = mi * 16 + quad * 4 + reg;
                Oh[lidx(row, j)] = (_Float16)tanhfast(acc[mi][t2][reg]);
            }
        }
    }
    __syncthreads();
#pragma unroll
    for (int it = 0; it < 4; ++it) {
        int c = it * 256 + tid;
        int row = c >> 4, kc = c & 15;
        int grow = m0 + row;
        if (grow < NN) {
            int ld = row * 128 + ((kc ^ (row & 15)) << 3);
            *(f16x8*)(H + (size_t)grow * HD + kc * 8) = *(const f16x8*)(&Oh[ld]);
        }
    }
}

// ---------------- aggregation: S[v] = sum_{in-edges} H[src], fp16 out ----------------
// [R2: fusing into GEMM regressed (needs max TLP) -- KEEP SPLIT.
//  R6: more MLP + pk_add pre-reduce cut VALUBusy 38->29% but dur FLAT; FETCH 177MB
//  == cross-XCD distinct-row floor (86.5K rows x 8 XCDs). STRUCTURAL ROOFLINE ~58us.
//  DO NOT TOUCH.]
__global__ void k_agg(const _Float16* __restrict__ H, const int* __restrict__ indptr,
                      const int* __restrict__ csr, _Float16* __restrict__ Shi) {
    int v = blockIdx.x * 4 + (threadIdx.x >> 6);
    int lane = threadIdx.x & 63;
    int slot = lane >> 4;
    int cg = lane & 15;
    const _Float16* hp = H + cg * 8;
    int s = indptr[v], e = indptr[v + 1];
    float a0 = 0.f, a1 = 0.f, a2 = 0.f, a3 = 0.f, a4 = 0.f, a5 = 0.f, a6 = 0.f, a7 = 0.f;
    int i = s + slot;
    for (; i + 12 < e; i += 16) {
        int u0 = csr[i], u1 = csr[i + 4], u2 = csr[i + 8], u3 = csr[i + 12];
        f16x8 t0 = *(const f16x8*)(hp + (size_t)u0 * HD);
        f16x8 t1 = *(const f16x8*)(hp + (size_t)u1 * HD);
        f16x8 t2 = *(const f16x8*)(hp + (size_t)u2 * HD);
        f16x8 t3 = *(const f16x8*)(hp + (size_t)u3 * HD);
        a0 += (float)t0[0] + (float)t1[0] + (float)t2[0] + (float)t3[0];
        a1 += (float)t0[1] + (float)t1[1] + (float)t2[1] + (float)t3[1];
        a2 += (float)t0[2] + (float)t1[2] + (float)t2[2] + (float)t3[2];
        a3 += (float)t0[3] + (float)t1[3] + (float)t2[3] + (float)t3[3];
        a4 += (float)t0[4] + (float)t1[4] + (float)t2[4] + (float)t3[4];
        a5 += (float)t0[5] + (float)t1[5] + (float)t2[5] + (float)t3[5];
        a6 += (float)t0[6] + (float)t1[6] + (float)t2[6] + (float)t3[6];
        a7 += (float)t0[7] + (float)t1[7] + (float)t2[7] + (float)t3[7];
    }
    for (; i < e; i += 4) {
        int u0 = csr[i];
        f16x8 t0 = *(const f16x8*)(hp + (size_t)u0 * HD);
        a0 += (float)t0[0]; a1 += (float)t0[1]; a2 += (float)t0[2]; a3 += (float)t0[3];
        a4 += (float)t0[4]; a5 += (float)t0[5]; a6 += (float)t0[6]; a7 += (float)t0[7];
    }
    a0 += __shfl_down(a0, 32); a1 += __shfl_down(a1, 32);
    a2 += __shfl_down(a2, 32); a3 += __shfl_down(a3, 32);
    a4 += __shfl_down(a4, 32); a5 += __shfl_down(a5, 32);
    a6 += __shfl_down(a6, 32); a7 += __shfl_down(a7, 32);
    a0 += __shfl_down(a0, 16); a1 += __shfl_down(a1, 16);
    a2 += __shfl_down(a2, 16); a3 += __shfl_down(a3, 16);
    a4 += __shfl_down(a4, 16); a5 += __shfl_down(a5, 16);
    a6 += __shfl_down(a6, 16); a7 += __shfl_down(a7, 16);
    if (lane < 16) {
        f16x8 o;
        o[0] = (_Float16)a0; o[1] = (_Float16)a1; o[2] = (_Float16)a2; o[3] = (_Float16)a3;
        o[4] = (_Float16)a4; o[5] = (_Float16)a5; o[6] = (_Float16)a6; o[7] = (_Float16)a7;
        *(f16x8*)(Shi + (size_t)v * HD + cg * 8) = o;
    }
}

// ---------------- fused MFMA GEMM + GRU gates (H fp16, in place) ----------------
// [R2: 64-row tile = 212 regs -> 2 blk/CU, 81us. R3: 32-row, acc[2][8], H staged via
//  PRIVATE regs (loads legally stay in flight across the barrier) committed to LDS
//  after S phases -> ~53us at 3 waves/SIMD. R7 post-mortem: global_load_lds staging
//  REGRESSED to 59us -- the DMA writes LDS, so the first barrier must drain vmcnt(0),
//  serializing ALL staging; it also kills the hreg defer (shared vmcnt counter).
//  KEEP the R3 reg-staged form.]
__global__ void __launch_bounds__(256, 3) k_ggemm(
        const _Float16* __restrict__ Shi, _Float16* __restrict__ H,
        const _Float16* __restrict__ Bsw,
        const float* __restrict__ bih, const float* __restrict__ bhh) {
    __shared__ _Float16 Sl[32 * 128];
    __shared__ _Float16 Hh[32 * 128];
    int tid = threadIdx.x;
    int w = tid >> 6, lane = tid & 63;
    int quad = lane >> 4, l16 = lane & 15;
    int m0 = blockIdx.x * 32;

    // stage: Sl -> LDS now; H -> regs (LDS write deferred under S-phase MFMAs)
    f16x8 hreg[2];
#pragma unroll
    for (int it = 0; it < 2; ++it) {
        int c = it * 256 + tid;
        int row = c >> 4, kc = c & 15;
        int grow = m0 + row;
        size_t gsrc = (size_t)grow * HD + kc * 8;
        int ld = row * 128 + ((kc ^ (row & 15)) << 3);
        *(f16x8*)(&Sl[ld]) = *(const f16x8*)(Shi + gsrc);
        hreg[it] = *(const f16x8*)(H + gsrc);
    }
    __syncthreads();

    f32x4 acc[2][8];
#pragma unroll
    for (int mi = 0; mi < 2; ++mi)
#pragma unroll
        for (int t = 0; t < 8; ++t) acc[mi][t] = (f32x4){0.f, 0.f, 0.f, 0.f};

    const _Float16* bw = Bsw + (size_t)(w * 8) * 8 * 512 + lane * 8;

    // S phases (gates r,z,i_n -> t=0..5); H global loads still in flight
#pragma unroll
    for (int p = 0; p < 4; ++p) {
        f16x8 a[2];
#pragma unroll
        for (int mi = 0; mi < 2; ++mi)
            a[mi] = *(const f16x8*)(&Sl[lidx(mi * 16 + l16, p * 32 + quad * 8)]);
#pragma unroll
        for (int t = 0; t < 6; ++t) {
            f16x8 b = *(const f16x8*)(bw + (size_t)(t * 8 + p) * 512);
#pragma unroll
            for (int mi = 0; mi < 2; ++mi)
                acc[mi][t] = __builtin_amdgcn_mfma_f32_16x16x32_f16(a[mi], b, acc[mi][t], 0, 0, 0);
        }
    }

    // now commit H regs -> LDS
#pragma unroll
    for (int it = 0; it < 2; ++it) {
        int c = it * 256 + tid;
        int row = c >> 4, kc = c & 15;
        int ld = row * 128 + ((kc ^ (row & 15)) << 3);
        *(f16x8*)(&Hh[ld]) = hreg[it];
    }
    __syncthreads();

    // H phases (gates r,z,h_n -> t={0,1,2,3,6,7})
#pragma unroll
    for (int p = 0; p < 4; ++p) {
        f16x8 a[2];
#pragma unroll
        for (int mi = 0; mi < 2; ++mi)
            a[mi] = *(const f16x8*)(&Hh[lidx(mi * 16 + l16, p * 32 + quad * 8)]);
#pragma unroll
        for (int tt = 0; tt < 6; ++tt) {
            int t = (tt < 4) ? tt : (tt + 2);
            f16x8 b = *(const f16x8*)(bw + (size_t)(t * 8 + p + 4) * 512);
#pragma unroll
            for (int mi = 0; mi < 2; ++mi)
                acc[mi][t] = __builtin_amdgcn_mfma_f32_16x16x32_f16(a[mi], b, acc[mi][t], 0, 0, 0);
        }
    }

    __syncthreads();   // all H-LDS A-reads done before epilogue overwrites Hh

    // epilogue: gates; in-place RMW on Hh (each li touched by exactly one thread)
#pragma unroll
    for (int ns = 0; ns < 2; ++ns) {
        int j = w * 32 + ns * 16 + l16;
        float br  = bih[j]       + bhh[j];
        float bz  = bih[j + 128] + bhh[j + 128];
        float bin = bih[j + 256];
        float bhn = bhh[j + 256];
#pragma unroll
        for (int mi = 0; mi < 2; ++mi) {
#pragma unroll
            for (int reg = 0; reg < 4; ++reg) {
                int row = mi * 16 + quad * 4 + reg;
                int li = lidx(row, j);
                float hold = (float)Hh[li];
                float r = sigm(acc[mi][0 + ns][reg] + br);
                float z = sigm(acc[mi][2 + ns][reg] + bz);
                float n = tanhfast(acc[mi][4 + ns][reg] + bin + r * (acc[mi][6 + ns][reg] + bhn));
                Hh[li] = (_Float16)((1.f - z) * n + z * hold);
            }
        }
    }
    __syncthreads();

#pragma unroll
    for (int it = 0; it < 2; ++it) {
        int c = it * 256 + tid;
        int row = c >> 4, kc = c & 15;
        int grow = m0 + row;
        int ld = row * 128 + ((kc ^ (row & 15)) << 3);
        *(f16x8*)(H + (size_t)grow * HD + kc * 8) = *(const f16x8*)(&Hh[ld]);
    }
}

// ---------------- pooling + head ----------------
__global__ void k_ginit(int* __restrict__ gs, int* __restrict__ ge) {
    int g = threadIdx.x;
    if (g < NG) { gs[g] = 0; ge[g] = 0; }
}

__global__ void k_bounds(const int* __restrict__ batch, int* __restrict__ gs, int* __restrict__ ge) {
    int i = blockIdx.x * 256 + threadIdx.x;
    if (i >= NN) return;
    int b = batch[i];
    if (i == 0 || batch[i - 1] != b) gs[b] = i;
    if (i == NN - 1 || batch[i + 1] != b) ge[b] = i + 1;
}

// [R3: old k_pool (scalar 2B loads, serial loop) was 68us, Occ 8%. R4: slot x colgroup
//  f16x8 restructure -> out of top-5. KEEP.]
__global__ void __launch_bounds__(256) k_pool(const _Float16* __restrict__ H,
                       const int* __restrict__ gs, const int* __restrict__ ge,
                       const float* __restrict__ Wp, const float* __restrict__ bp,
                       float* __restrict__ out) {
    __shared__ float red[4][HD];
    __shared__ float red2[HD];
    int g = blockIdx.x, tid = threadIdx.x;
    int w = tid >> 6, lane = tid & 63;
    int slot = tid >> 4;        // 0..15 (global node-slot)
    int cg = tid & 15;          // col-group of 8
    int s = gs[g], e = ge[g];
    float a0 = 0.f, a1 = 0.f, a2 = 0.f, a3 = 0.f, a4 = 0.f, a5 = 0.f, a6 = 0.f, a7 = 0.f;
    for (int n = s + slot; n < e; n += 16) {
        f16x8 v = *(const f16x8*)(H + (size_t)n * HD + cg * 8);
        a0 += (float)v[0]; a1 += (float)v[1]; a2 += (float)v[2]; a3 += (float)v[3];
        a4 += (float)v[4]; a5 += (float)v[5]; a6 += (float)v[6]; a7 += (float)v[7];
    }
    // reduce the 4 slot-locals within each wave
    a0 += __shfl_down(a0, 32); a1 += __shfl_down(a1, 32);
    a2 += __shfl_down(a2, 32); a3 += __shfl_down(a3, 32);
    a4 += __shfl_down(a4, 32); a5 += __shfl_down(a5, 32);
    a6 += __shfl_down(a6, 32); a7 += __shfl_down(a7, 32);
    a0 += __shfl_down(a0, 16); a1 += __shfl_down(a1, 16);
    a2 += __shfl_down(a2, 16); a3 += __shfl_down(a3, 16);
    a4 += __shfl_down(a4, 16); a5 += __shfl_down(a5, 16);
    a6 += __shfl_down(a6, 16); a7 += __shfl_down(a7, 16);
    if (lane < 16) {
        red[w][cg * 8 + 0] = a0; red[w][cg * 8 + 1] = a1;
        red[w][cg * 8 + 2] = a2; red[w][cg * 8 + 3] = a3;
        red[w][cg * 8 + 4] = a4; red[w][cg * 8 + 5] = a5;
        red[w][cg * 8 + 6] = a6; red[w][cg * 8 + 7] = a7;
    }
    __syncthreads();
    if (tid < HD) {
        int cnt = e - s;
        float pooled = (red[0][tid] + red[1][tid] + red[2][tid] + red[3][tid])
                       / (float)(cnt > 0 ? cnt : 1);
        red2[tid] = fmaxf(pooled, 0.f) * Wp[tid];
    }
    __syncthreads();
    for (int off = 64; off > 0; off >>= 1) {
        if (tid < off) red2[tid] += red2[tid + off];
        __syncthreads();
    }
    if (tid == 0) out[g] = red2[0] + bp[0];
}

extern "C" void kernel_launch(void* const* d_in, const int* in_sizes, int n_in,
                              void* d_out, int out_size, void* d_ws, size_t ws_size,
                              hipStream_t stream) {
    const float* x   = (const float*)d_in[0];
    const int*   ei  = (const int*)d_in[1];
    const int*   bat = (const int*)d_in[2];
    const float* Win = (const float*)d_in[3];
    const float* Wmp = (const float*)d_in[4];
    const float* Wih = (const float*)d_in[5];
    const float* Whh = (const float*)d_in[6];
    const float* bih = (const float*)d_in[7];
    const float* bhh = (const float*)d_in[8];
    const float* Wp  = (const float*)d_in[9];
    const float* bp  = (const float*)d_in[10];
    float* out = (float*)d_out;

    const int* esrc = ei;
    const int* edst = ei + NE;

    char* w = (char*)d_ws;
    _Float16* H   = (_Float16*)w; w += (size_t)NN * HD * 2;
    _Float16* Shi = (_Float16*)w; w += (size_t)NN * HD * 2;
    _Float16* Bsw = (_Float16*)w; w += (size_t)NSTEP * 131072 * 2;
    _Float16* BihW = (_Float16*)w; w += 8192 * 2;
    _Float16* BilW = (_Float16*)w; w += 8192 * 2;
    int* indptr  = (int*)w;   w += 400128;
    int* scratch = (int*)w;   w += 400128;   // bcur (782) @ +0; bbase (783) @ +1024
    int* csr     = (int*)w;   w += (size_t)NE * 4;
    int* gs      = (int*)w;   w += NG * 4;
    int* ge      = (int*)w;   w += NG * 4;

    int*  bcur  = scratch;
    int*  bbase = scratch + 1024;
    // pairs buffer aliases Shi (19.2MB < 25.6MB; consumed by k_fill2 before first k_agg)
    int2* pairs = (int2*)Shi;

    // CSR build: bin into fixed-cap bucket windows -> 782-scan -> per-bucket indptr+fill
    hipMemsetAsync(bcur, 0, NBUCK * 4, stream);
    k_bin<<<BINBLK, 256, 0, stream>>>(esrc, edst, bcur, pairs);
    k_bscan<<<1, 1024, 0, stream>>>(bcur, bbase);
    k_fill2<<<NBUCK, 256, 0, stream>>>(pairs, bcur, bbase, indptr, csr);

    // weight prep + input layer
    k_prepB<<<NSTEP * 512, 256, 0, stream>>>(Wmp, Wih, Whh, Bsw);
    k_prepWin<<<32, 256, 0, stream>>>(Win, BihW, BilW);
    k_input<<<(NN + 63) / 64, 256, 0, stream>>>(x, BihW, BilW, H);

    // 6 message-passing + fused GEMM/GRU steps (H updated in place)
    for (int st = 0; st < NSTEP; ++st) {
        k_agg<<<NN / 4, 256, 0, stream>>>(H, indptr, csr, Shi);
        k_ggemm<<<NN / 32, 256, 0, stream>>>(Shi, H,
                                             Bsw + (size_t)st * 131072,
                                             bih, bhh);
    }

    // pooling + head
    k_ginit<<<1, NG, 0, stream>>>(gs, ge);
    k_bounds<<<(NN + 255) / 256, 256, 0, stream>>>(bat, gs, ge);
    k_pool<<<NG, 256, 0, stream>>>(H, gs, ge, Wp, bp, out);
}

// Round 9
// 786.230 us; speedup vs baseline: 1.0736x; 1.0270x over previous
//
#include <hip/hip_runtime.h>

#define NN 100000
#define NE 1600000
#define NG 512
#define FIN 64
#define HD 128
#define NSTEP 6

// ---- bucketed CSR build geometry ----
#define BROWS 128               // dst nodes per bucket
#define NBUCK 782               // ceil(NN/BROWS)
#define BCAP 3072               // fixed pairs-capacity per bucket (mean 2048, sigma~45 -> 22-sigma headroom)
#define EPER 16                 // edges per thread in k_bin
#define BINBLK 391              // ceil(NE / (256*EPER))

typedef _Float16 f16x8 __attribute__((ext_vector_type(8)));
typedef _Float16 f16x4 __attribute__((ext_vector_type(4)));
typedef float    f32x4 __attribute__((ext_vector_type(4)));

__device__ __forceinline__ float sigm(float x) { return 1.f / (1.f + __expf(-x)); }
__device__ __forceinline__ float tanhfast(float x) { return 2.f / (1.f + __expf(-2.f * x)) - 1.f; }

// LDS tile index with XOR swizzle (128-col tiles, 16B chunks)
__device__ __forceinline__ int lidx(int r, int col) {
    return r * 128 + ((((col >> 3) ^ (r & 15)) << 3) | (col & 7));
}

// ---------------- CSR build ----------------
// [R0: direct-scatter fill = 105MB write-amp, 126us. R1: bucketed 2-phase = ~25us.
//  R5: k_count + 3-kernel scan ELIMINATED via fixed-BCAP bucket windows (saved 70us). KEEP.]

// phase 1: bin (src,dst) pairs into fixed-capacity per-bucket windows
__global__ void __launch_bounds__(256) k_bin(const int* __restrict__ src, const int* __restrict__ dst,
                                             int* __restrict__ bcur, int2* __restrict__ pairs) {
    __shared__ int hist[NBUCK];
    __shared__ int base[NBUCK];
    int tid = threadIdx.x;
    for (int i = tid; i < NBUCK; i += 256) hist[i] = 0;
    __syncthreads();
    int e0 = blockIdx.x * (256 * EPER) + tid;
    int s[EPER], d[EPER], rk[EPER];
#pragma unroll
    for (int k = 0; k < EPER; ++k) {
        int e = e0 + k * 256;
        if (e < NE) {
            s[k] = src[e];
            d[k] = dst[e];
            rk[k] = atomicAdd(&hist[d[k] >> 7], 1);   // LDS atomic: local rank within (block,bucket)
        }
    }
    __syncthreads();
    for (int i = tid; i < NBUCK; i += 256) {
        int c = hist[i];
        base[i] = c ? atomicAdd(&bcur[i], c) : 0;     // one global atomic per (block,bucket); bcur starts at 0
    }
    __syncthreads();
#pragma unroll
    for (int k = 0; k < EPER; ++k) {
        int e = e0 + k * 256;
        if (e < NE) {
            int b = d[k] >> 7;
            pairs[(size_t)b * BCAP + base[b] + rk[k]] = make_int2(s[k], d[k]);
        }
    }
}

// scan 782 bucket counts -> bucket bases (1 block, 1024 threads)
__global__ void k_bscan(const int* __restrict__ bcnt, int* __restrict__ bbase) {
    __shared__ int sh[1024];
    int tid = threadIdx.x;
    int v = (tid < NBUCK) ? bcnt[tid] : 0;
    sh[tid] = v;
    __syncthreads();
    for (int off = 1; off < 1024; off <<= 1) {
        int t = (tid >= off) ? sh[tid - off] : 0;
        __syncthreads();
        sh[tid] += t;
        __syncthreads();
    }
    if (tid < NBUCK) bbase[tid] = sh[tid] - v;
    if (tid == NBUCK - 1) bbase[NBUCK] = sh[tid];    // = NE
}

// phase 2: one block per bucket; rebuild per-node indptr + dense csr window
__global__ void __launch_bounds__(256) k_fill2(const int2* __restrict__ pairs,
                                               const int* __restrict__ bcnt,
                                               const int* __restrict__ bbase,
                                               int* __restrict__ indptr,
                                               int* __restrict__ csr) {
    __shared__ int cnt[BROWS];
    __shared__ int ip[BROWS];
    __shared__ int sc[BROWS];
    int b = blockIdx.x, tid = threadIdx.x;
    int n0 = b * BROWS;
    if (tid < BROWS) cnt[tid] = 0;
    __syncthreads();
    int ec = bcnt[b];
    const int2* pw = pairs + (size_t)b * BCAP;
    // pass A: per-node counts within bucket
    for (int i = tid; i < ec; i += 256)
        atomicAdd(&cnt[pw[i].y & (BROWS - 1)], 1);
    __syncthreads();
    // exclusive scan of 128 counts
    if (tid < BROWS) sc[tid] = cnt[tid];
    __syncthreads();
    for (int off = 1; off < BROWS; off <<= 1) {
        int t = (tid < BROWS && tid >= off) ? sc[tid - off] : 0;
        __syncthreads();
        if (tid < BROWS) sc[tid] += t;
        __syncthreads();
    }
    int base = bbase[b];
    if (tid < BROWS) {
        int v = base + sc[tid] - cnt[tid];
        ip[tid] = v;
        int n = n0 + tid;
        if (n < NN) indptr[n] = v;
        cnt[tid] = 0;
    }
    if (b == NBUCK - 1 && tid == 0) indptr[NN] = NE;
    __syncthreads();
    // pass B: place edges (bucket window is L2-hot from pass A)
    for (int i = tid; i < ec; i += 256) {
        int2 p = pw[i];
        int li = p.y & (BROWS - 1);
        int r = atomicAdd(&cnt[li], 1);
        csr[ip[li] + r] = p.x;
    }
}

// ---------------- B prep (GRU weights), swizzled to MFMA fragment order ----------------
// Logical Bcat[c][k]: c=0..511 (g=c>>7: 0=r,1=z,2=i_n,3=h_n; j=c&127), k=0..255.
//   k<128:  g!=3 ? Weff[s][k][jj] : 0    (Weff = Wmp[s] @ Wih^T)
//   k>=128: g!=2 ? Whh[jj][k-128] : 0
__global__ void k_prepB(const float* __restrict__ Wmp, const float* __restrict__ Wih,
                        const float* __restrict__ Whh, _Float16* __restrict__ Bsw) {
    __shared__ float wih[HD];
    int b = blockIdx.x;          // s*512 + c
    int s = b >> 9;
    int c = b & 511;
    int g = c >> 7;
    int j = c & 127;
    int jj = (g < 2) ? c : (j + 256);
    int k = threadIdx.x;         // 0..255
    if (k < HD) wih[k] = Wih[(size_t)jj * HD + k];
    __syncthreads();
    float val = 0.f;
    if (k < 128) {
        if (g != 3) {
            const float* wm = Wmp + ((size_t)s * HD + k) * HD;
            float acc = 0.f;
#pragma unroll 8
            for (int t = 0; t < HD; ++t) acc += wm[t] * wih[t];
            val = acc;
        }
    } else {
        if (g != 2) val = Whh[(size_t)jj * HD + (k - 128)];
    }
    int l16 = c & 15, sub = (c >> 4) & 1, w = (c >> 5) & 3;
    int t = g * 2 + sub;
    int p = k >> 5, quad = (k >> 3) & 3, je = k & 7;
    size_t idx = (size_t)s * 131072 + ((size_t)((w * 8 + t) * 8 + p) * 64 + quad * 16 + l16) * 8 + je;
    Bsw[idx] = (_Float16)val;
}

// ---------------- W_in prep: fragment-order hi/lo fp16 ----------------
__global__ void k_prepWin(const float* __restrict__ Win,
                          _Float16* __restrict__ BihW, _Float16* __restrict__ BilW) {
    int gid = blockIdx.x * 256 + threadIdx.x;   // 0..8191
    int jj = gid & 7;
    int lane = (gid >> 3) & 63;
    int p = (gid >> 9) & 1;
    int t = (gid >> 10) & 7;
    int k = p * 32 + (lane >> 4) * 8 + jj;
    int col = t * 16 + (lane & 15);
    float val = Win[(size_t)k * HD + col];
    _Float16 hi = (_Float16)val;
    BihW[gid] = hi;
    BilW[gid] = (_Float16)(val - (float)hi);
}

// ---------------- input layer (MFMA): h = tanh(x @ W_in), fp16 out ----------------
__global__ void __launch_bounds__(256) k_input(const float* __restrict__ x,
                                               const _Float16* __restrict__ BihW,
                                               const _Float16* __restrict__ BilW,
                                               _Float16* __restrict__ H) {
    __shared__ _Float16 Xh[64 * 64];
    __shared__ _Float16 Xl[64 * 64];
    __shared__ _Float16 Oh[64 * 128];
    int tid = threadIdx.x;
    int w = tid >> 6, lane = tid & 63;
    int quad = lane >> 4, l16 = lane & 15;
    int m0 = blockIdx.x * 64;

#pragma unroll
    for (int it = 0; it < 4; ++it) {
        int c = it * 256 + tid;          // 1024 chunks of 4 floats
        int row = c >> 4, cc = c & 15;
        int grow = m0 + row; if (grow >= NN) grow = NN - 1;
        float4 v = ((const float4*)(x + (size_t)grow * FIN))[cc];
        f16x4 vh, vl;
        vh[0] = (_Float16)v.x; vl[0] = (_Float16)(v.x - (float)vh[0]);
        vh[1] = (_Float16)v.y; vl[1] = (_Float16)(v.y - (float)vh[1]);
        vh[2] = (_Float16)v.z; vl[2] = (_Float16)(v.z - (float)vh[2]);
        vh[3] = (_Float16)v.w; vl[3] = (_Float16)(v.w - (float)vh[3]);
        int ld = row * 64 + ((((cc >> 1) ^ (row & 7)) << 3)) + (cc & 1) * 4;
        *(f16x4*)(&Xh[ld]) = vh;
        *(f16x4*)(&Xl[ld]) = vl;
    }
    __syncthreads();

    f32x4 acc[4][2];
#pragma unroll
    for (int mi = 0; mi < 4; ++mi) { acc[mi][0] = (f32x4){0,0,0,0}; acc[mi][1] = (f32x4){0,0,0,0}; }

#pragma unroll
    for (int p = 0; p < 2; ++p) {
        int ch = p * 4 + quad;
        f16x8 ah[4], al[4];
#pragma unroll
        for (int mi = 0; mi < 4; ++mi) {
            int r = mi * 16 + l16;
            int li = r * 64 + ((ch ^ (r & 7)) << 3);
            ah[mi] = *(const f16x8*)(&Xh[li]);
            al[mi] = *(const f16x8*)(&Xl[li]);
        }
#pragma unroll
        for (int t2 = 0; t2 < 2; ++t2) {
            int t = w * 2 + t2;
            f16x8 bh = *(const f16x8*)(BihW + ((size_t)(t * 2 + p) * 64 + lane) * 8);
            f16x8 blv = *(const f16x8*)(BilW + ((size_t)(t * 2 + p) * 64 + lane) * 8);
#pragma unroll
            for (int mi = 0; mi < 4; ++mi) {
                acc[mi][t2] = __builtin_amdgcn_mfma_f32_16x16x32_f16(ah[mi], bh, acc[mi][t2], 0, 0, 0);
                acc[mi][t2] = __builtin_amdgcn_mfma_f32_16x16x32_f16(ah[mi], blv, acc[mi][t2], 0, 0, 0);
                acc[mi][t2] = __builtin_amdgcn_mfma_f32_16x16x32_f16(al[mi], bh, acc[mi][t2], 0, 0, 0);
            }
        }
    }

#pragma unroll
    for (int t2 = 0; t2 < 2; ++t2) {
        int j = (w * 2 + t2) * 16 + l16;
#pragma unroll
        for (int mi = 0; mi < 4; ++mi) {
#pragma unroll
            for (int reg = 0; reg < 4; ++reg) {
                int row = mi * 16 + quad * 4 + reg;
                Oh[lidx(row, j)] = (_Float16)tanhfast(acc[mi][t2][reg]);
            }
        }
    }
    __syncthreads();
#pragma unroll
    for (int it = 0; it < 4; ++it) {
        int c = it * 256 + tid;
        int row = c >> 4, kc = c & 15;
        int grow = m0 + row;
        if (grow < NN) {
            int ld = row * 128 + ((kc ^ (row & 15)) << 3);
            *(f16x8*)(H + (size_t)grow * HD + kc * 8) = *(const f16x8*)(&Oh[ld]);
        }
    }
}

// ---------------- aggregation: S[v] = sum_{in-edges} H[src], fp16 out ----------------
// [R2: fusing into GEMM regressed (needs max TLP) -- KEEP SPLIT.
//  R6: more MLP + pk_add pre-reduce cut VALUBusy 38->29% but dur FLAT; FETCH 177MB
//  == cross-XCD distinct-row floor (86.5K rows x 8 XCDs). STRUCTURAL ROOFLINE ~58us.
//  DO NOT TOUCH.]
__global__ void k_agg(const _Float16* __restrict__ H, const int* __restrict__ indptr,
                      const int* __restrict__ csr, _Float16* __restrict__ Shi) {
    int v = blockIdx.x * 4 + (threadIdx.x >> 6);
    int lane = threadIdx.x & 63;
    int slot = lane >> 4;
    int cg = lane & 15;
    const _Float16* hp = H + cg * 8;
    int s = indptr[v], e = indptr[v + 1];
    float a0 = 0.f, a1 = 0.f, a2 = 0.f, a3 = 0.f, a4 = 0.f, a5 = 0.f, a6 = 0.f, a7 = 0.f;
    int i = s + slot;
    for (; i + 12 < e; i += 16) {
        int u0 = csr[i], u1 = csr[i + 4], u2 = csr[i + 8], u3 = csr[i + 12];
        f16x8 t0 = *(const f16x8*)(hp + (size_t)u0 * HD);
        f16x8 t1 = *(const f16x8*)(hp + (size_t)u1 * HD);
        f16x8 t2 = *(const f16x8*)(hp + (size_t)u2 * HD);
        f16x8 t3 = *(const f16x8*)(hp + (size_t)u3 * HD);
        a0 += (float)t0[0] + (float)t1[0] + (float)t2[0] + (float)t3[0];
        a1 += (float)t0[1] + (float)t1[1] + (float)t2[1] + (float)t3[1];
        a2 += (float)t0[2] + (float)t1[2] + (float)t2[2] + (float)t3[2];
        a3 += (float)t0[3] + (float)t1[3] + (float)t2[3] + (float)t3[3];
        a4 += (float)t0[4] + (float)t1[4] + (float)t2[4] + (float)t3[4];
        a5 += (float)t0[5] + (float)t1[5] + (float)t2[5] + (float)t3[5];
        a6 += (float)t0[6] + (float)t1[6] + (float)t2[6] + (float)t3[6];
        a7 += (float)t0[7] + (float)t1[7] + (float)t2[7] + (float)t3[7];
    }
    for (; i < e; i += 4) {
        int u0 = csr[i];
        f16x8 t0 = *(const f16x8*)(hp + (size_t)u0 * HD);
        a0 += (float)t0[0]; a1 += (float)t0[1]; a2 += (float)t0[2]; a3 += (float)t0[3];
        a4 += (float)t0[4]; a5 += (float)t0[5]; a6 += (float)t0[6]; a7 += (float)t0[7];
    }
    a0 += __shfl_down(a0, 32); a1 += __shfl_down(a1, 32);
    a2 += __shfl_down(a2, 32); a3 += __shfl_down(a3, 32);
    a4 += __shfl_down(a4, 32); a5 += __shfl_down(a5, 32);
    a6 += __shfl_down(a6, 32); a7 += __shfl_down(a7, 32);
    a0 += __shfl_down(a0, 16); a1 += __shfl_down(a1, 16);
    a2 += __shfl_down(a2, 16); a3 += __shfl_down(a3, 16);
    a4 += __shfl_down(a4, 16); a5 += __shfl_down(a5, 16);
    a6 += __shfl_down(a6, 16); a7 += __shfl_down(a7, 16);
    if (lane < 16) {
        f16x8 o;
        o[0] = (_Float16)a0; o[1] = (_Float16)a1; o[2] = (_Float16)a2; o[3] = (_Float16)a3;
        o[4] = (_Float16)a4; o[5] = (_Float16)a5; o[6] = (_Float16)a6; o[7] = (_Float16)a7;
        *(f16x8*)(Shi + (size_t)v * HD + cg * 8) = o;
    }
}

// ---------------- fused MFMA GEMM + GRU gates (H fp16, in place) ----------------
// [R2: 64-row = 2 waves/SIMD, 81us. R3: 32-row, acc[2][8], reg-staged H -> ~53us at
//  3 waves/SIMD (~148 regs, acc=64 AGPR dominates). R7: global_load_lds regressed
//  (barrier drains vmcnt(0), kills the hreg defer). R9: SUB-HALF SPLIT -- the
//  t = 2g+sub structure is separable by sub: half h uses only t in {h,2+h,4+h,6+h},
//  disjoint acc/B/epilogue. Each block does one 16-j half per wave: acc[2][4] =
//  32 AGPR, ~85 regs -> 5-6 waves/SIMD. Grid 6250. Bsw layout unchanged; A-tile
//  staged twice (L3-absorbed). Occupancy is THE proven lever on this kernel (R3).]
__global__ void __launch_bounds__(256, 4) k_ggemm(
        const _Float16* __restrict__ Shi, _Float16* __restrict__ H,
        const _Float16* __restrict__ Bsw,
        const float* __restrict__ bih, const float* __restrict__ bhh) {
    __shared__ _Float16 Sl[32 * 128];
    __shared__ _Float16 Hh[32 * 128];
    int tid = threadIdx.x;
    int w = tid >> 6, lane = tid & 63;
    int quad = lane >> 4, l16 = lane & 15;
    int bid = blockIdx.x;
    int m0 = (bid >> 1) * 32;
    int h = bid & 1;               // sub-half: t = 2g + h

    // stage: Sl -> LDS now; H -> regs (LDS write deferred under S-phase MFMAs)
    f16x8 hreg[2];
#pragma unroll
    for (int it = 0; it < 2; ++it) {
        int c = it * 256 + tid;
        int row = c >> 4, kc = c & 15;
        size_t gsrc = (size_t)(m0 + row) * HD + kc * 8;
        int ld = row * 128 + ((kc ^ (row & 15)) << 3);
        *(f16x8*)(&Sl[ld]) = *(const f16x8*)(Shi + gsrc);
        hreg[it] = *(const f16x8*)(H + gsrc);
    }
    __syncthreads();

    // acc[mi][g]: g = 0:r, 1:z, 2:i_n, 3:h_n
    f32x4 acc[2][4];
#pragma unroll
    for (int mi = 0; mi < 2; ++mi)
#pragma unroll
        for (int g = 0; g < 4; ++g) acc[mi][g] = (f32x4){0.f, 0.f, 0.f, 0.f};

    const _Float16* bw = Bsw + (size_t)(w * 8) * 8 * 512 + lane * 8;

    // S phases: gates r,z,i_n (g=0,1,2), t = 2g+h; H loads still in flight
#pragma unroll
    for (int p = 0; p < 4; ++p) {
        f16x8 a[2];
#pragma unroll
        for (int mi = 0; mi < 2; ++mi)
            a[mi] = *(const f16x8*)(&Sl[lidx(mi * 16 + l16, p * 32 + quad * 8)]);
#pragma unroll
        for (int g = 0; g < 3; ++g) {
            int t = g * 2 + h;
            f16x8 b = *(const f16x8*)(bw + (size_t)(t * 8 + p) * 512);
#pragma unroll
            for (int mi = 0; mi < 2; ++mi)
                acc[mi][g] = __builtin_amdgcn_mfma_f32_16x16x32_f16(a[mi], b, acc[mi][g], 0, 0, 0);
        }
    }

    // now commit H regs -> LDS
#pragma unroll
    for (int it = 0; it < 2; ++it) {
        int c = it * 256 + tid;
        int row = c >> 4, kc = c & 15;
        int ld = row * 128 + ((kc ^ (row & 15)) << 3);
        *(f16x8*)(&Hh[ld]) = hreg[it];
    }
    __syncthreads();

    // H phases: gates r,z,h_n (g=0,1,3), t = 2g+h
#pragma unroll
    for (int p = 0; p < 4; ++p) {
        f16x8 a[2];
#pragma unroll
        for (int mi = 0; mi < 2; ++mi)
            a[mi] = *(const f16x8*)(&Hh[lidx(mi * 16 + l16, p * 32 + quad * 8)]);
#pragma unroll
        for (int gg = 0; gg < 3; ++gg) {
            int g = (gg < 2) ? gg : 3;
            int t = g * 2 + h;
            f16x8 b = *(const f16x8*)(bw + (size_t)(t * 8 + p + 4) * 512);
#pragma unroll
            for (int mi = 0; mi < 2; ++mi)
                acc[mi][g] = __builtin_amdgcn_mfma_f32_16x16x32_f16(a[mi], b, acc[mi][g], 0, 0, 0);
        }
    }

    __syncthreads();   // all H-LDS A-reads done before epilogue overwrites Hh

    // epilogue: one j per thread; in-place RMW on Hh (own 16-col stripes only)
    {
        int j = w * 32 + h * 16 + l16;
        float br  = bih[j]       + bhh[j];
        float bz  = bih[j + 128] + bhh[j + 128];
        float bin = bih[j + 256];
        float bhn = bhh[j + 256];
#pragma unroll
        for (int mi = 0; mi < 2; ++mi) {
#pragma unroll
            for (int reg = 0; reg < 4; ++reg) {
                int row = mi * 16 + quad * 4 + reg;
                int li = lidx(row, j);
                float hold = (float)Hh[li];
                float r = sigm(acc[mi][0][reg] + br);
                float z = sigm(acc[mi][1][reg] + bz);
                float n = tanhfast(acc[mi][2][reg] + bin + r * (acc[mi][3][reg] + bhn));
                Hh[li] = (_Float16)((1.f - z) * n + z * hold);
            }
        }
    }
    __syncthreads();

    // write back own stripes: kc with bit1 == h (32 rows x 8 kc = 256 chunks)
    {
        int row = tid >> 3, ki = tid & 7;
        int kc = ((ki >> 1) << 2) + (h << 1) + (ki & 1);
        int ld = row * 128 + ((kc ^ (row & 15)) << 3);
        *(f16x8*)(H + (size_t)(m0 + row) * HD + kc * 8) = *(const f16x8*)(&Hh[ld]);
    }
}

// ---------------- pooling + head ----------------
__global__ void k_ginit(int* __restrict__ gs, int* __restrict__ ge) {
    int g = threadIdx.x;
    if (g < NG) { gs[g] = 0; ge[g] = 0; }
}

__global__ void k_bounds(const int* __restrict__ batch, int* __restrict__ gs, int* __restrict__ ge) {
    int i = blockIdx.x * 256 + threadIdx.x;
    if (i >= NN) return;
    int b = batch[i];
    if (i == 0 || batch[i - 1] != b) gs[b] = i;
    if (i == NN - 1 || batch[i + 1] != b) ge[b] = i + 1;
}

// [R3: old k_pool (scalar 2B loads, serial loop) was 68us, Occ 8%. R4: slot x colgroup
//  f16x8 restructure -> out of top-5. KEEP.]
__global__ void __launch_bounds__(256) k_pool(const _Float16* __restrict__ H,
                       const int* __restrict__ gs, const int* __restrict__ ge,
                       const float* __restrict__ Wp, const float* __restrict__ bp,
                       float* __restrict__ out) {
    __shared__ float red[4][HD];
    __shared__ float red2[HD];
    int g = blockIdx.x, tid = threadIdx.x;
    int w = tid >> 6, lane = tid & 63;
    int slot = tid >> 4;        // 0..15 (global node-slot)
    int cg = tid & 15;          // col-group of 8
    int s = gs[g], e = ge[g];
    float a0 = 0.f, a1 = 0.f, a2 = 0.f, a3 = 0.f, a4 = 0.f, a5 = 0.f, a6 = 0.f, a7 = 0.f;
    for (int n = s + slot; n < e; n += 16) {
        f16x8 v = *(const f16x8*)(H + (size_t)n * HD + cg * 8);
        a0 += (float)v[0]; a1 += (float)v[1]; a2 += (float)v[2]; a3 += (float)v[3];
        a4 += (float)v[4]; a5 += (float)v[5]; a6 += (float)v[6]; a7 += (float)v[7];
    }
    // reduce the 4 slot-locals within each wave
    a0 += __shfl_down(a0, 32); a1 += __shfl_down(a1, 32);
    a2 += __shfl_down(a2, 32); a3 += __shfl_down(a3, 32);
    a4 += __shfl_down(a4, 32); a5 += __shfl_down(a5, 32);
    a6 += __shfl_down(a6, 32); a7 += __shfl_down(a7, 32);
    a0 += __shfl_down(a0, 16); a1 += __shfl_down(a1, 16);
    a2 += __shfl_down(a2, 16); a3 += __shfl_down(a3, 16);
    a4 += __shfl_down(a4, 16); a5 += __shfl_down(a5, 16);
    a6 += __shfl_down(a6, 16); a7 += __shfl_down(a7, 16);
    if (lane < 16) {
        red[w][cg * 8 + 0] = a0; red[w][cg * 8 + 1] = a1;
        red[w][cg * 8 + 2] = a2; red[w][cg * 8 + 3] = a3;
        red[w][cg * 8 + 4] = a4; red[w][cg * 8 + 5] = a5;
        red[w][cg * 8 + 6] = a6; red[w][cg * 8 + 7] = a7;
    }
    __syncthreads();
    if (tid < HD) {
        int cnt = e - s;
        float pooled = (red[0][tid] + red[1][tid] + red[2][tid] + red[3][tid])
                       / (float)(cnt > 0 ? cnt : 1);
        red2[tid] = fmaxf(pooled, 0.f) * Wp[tid];
    }
    __syncthreads();
    for (int off = 64; off > 0; off >>= 1) {
        if (tid < off) red2[tid] += red2[tid + off];
        __syncthreads();
    }
    if (tid == 0) out[g] = red2[0] + bp[0];
}

extern "C" void kernel_launch(void* const* d_in, const int* in_sizes, int n_in,
                              void* d_out, int out_size, void* d_ws, size_t ws_size,
                              hipStream_t stream) {
    const float* x   = (const float*)d_in[0];
    const int*   ei  = (const int*)d_in[1];
    const int*   bat = (const int*)d_in[2];
    const float* Win = (const float*)d_in[3];
    const float* Wmp = (const float*)d_in[4];
    const float* Wih = (const float*)d_in[5];
    const float* Whh = (const float*)d_in[6];
    const float* bih = (const float*)d_in[7];
    const float* bhh = (const float*)d_in[8];
    const float* Wp  = (const float*)d_in[9];
    const float* bp  = (const float*)d_in[10];
    float* out = (float*)d_out;

    const int* esrc = ei;
    const int* edst = ei + NE;

    char* w = (char*)d_ws;
    _Float16* H   = (_Float16*)w; w += (size_t)NN * HD * 2;
    _Float16* Shi = (_Float16*)w; w += (size_t)NN * HD * 2;
    _Float16* Bsw = (_Float16*)w; w += (size_t)NSTEP * 131072 * 2;
    _Float16* BihW = (_Float16*)w; w += 8192 * 2;
    _Float16* BilW = (_Float16*)w; w += 8192 * 2;
    int* indptr  = (int*)w;   w += 400128;
    int* scratch = (int*)w;   w += 400128;   // bcur (782) @ +0; bbase (783) @ +1024
    int* csr     = (int*)w;   w += (size_t)NE * 4;
    int* gs      = (int*)w;   w += NG * 4;
    int* ge      = (int*)w;   w += NG * 4;

    int*  bcur  = scratch;
    int*  bbase = scratch + 1024;
    // pairs buffer aliases Shi (19.2MB < 25.6MB; consumed by k_fill2 before first k_agg)
    int2* pairs = (int2*)Shi;

    // CSR build: bin into fixed-cap bucket windows -> 782-scan -> per-bucket indptr+fill
    hipMemsetAsync(bcur, 0, NBUCK * 4, stream);
    k_bin<<<BINBLK, 256, 0, stream>>>(esrc, edst, bcur, pairs);
    k_bscan<<<1, 1024, 0, stream>>>(bcur, bbase);
    k_fill2<<<NBUCK, 256, 0, stream>>>(pairs, bcur, bbase, indptr, csr);

    // weight prep + input layer
    k_prepB<<<NSTEP * 512, 256, 0, stream>>>(Wmp, Wih, Whh, Bsw);
    k_prepWin<<<32, 256, 0, stream>>>(Win, BihW, BilW);
    k_input<<<(NN + 63) / 64, 256, 0, stream>>>(x, BihW, BilW, H);

    // 6 message-passing + fused GEMM/GRU steps (H updated in place)
    for (int st = 0; st < NSTEP; ++st) {
        k_agg<<<NN / 4, 256, 0, stream>>>(H, indptr, csr, Shi);
        k_ggemm<<<(NN / 32) * 2, 256, 0, stream>>>(Shi, H,
                                                   Bsw + (size_t)st * 131072,
                                                   bih, bhh);
    }

    // pooling + head
    k_ginit<<<1, NG, 0, stream>>>(gs, ge);
    k_bounds<<<(NN + 255) / 256, 256, 0, stream>>>(bat, gs, ge);
    k_pool<<<NG, 256, 0, stream>>>(H, gs, ge, Wp, bp, out);
}